// Round 2
// baseline (262.412 us; speedup 1.0000x reference)
//
#include <hip/hip_runtime.h>
#include <stdint.h>

// Shapes (fixed for this problem)
#define B_   4
#define H_   16
#define S_   1024
#define D_   128
#define BM   128                 // Q rows per block
#define BN   64                  // K/V rows per iteration
#define NKT  (S_ / BN)           // 16
#define NTHREADS 512             // 8 waves; each wave owns 16 q-rows

typedef float f32x4 __attribute__((ext_vector_type(4)));
typedef short s16x8 __attribute__((ext_vector_type(8)));   // 8 bf16 (MFMA A/B frag)
typedef short s16x4 __attribute__((ext_vector_type(4)));
typedef int   i32x4 __attribute__((ext_vector_type(4)));

static __device__ __forceinline__ uint16_t f2bf(float f) {
  uint32_t u = __float_as_uint(f);
  u += 0x7FFFu + ((u >> 16) & 1u);          // round-to-nearest-even
  return (uint16_t)(u >> 16);
}
static __device__ __forceinline__ float bf2f(uint16_t h) {
  return __uint_as_float((uint32_t)h << 16);
}

// LDS map (80 KB -> 2 blocks/CU):
//  [ 0K,16K) lK buf0   [16K,32K) lK buf1   K tile  [64][128] bf16, XOR-swizzled
//  [32K,48K) lV buf0   [48K,64K) lV buf1   V^T tile [128][64] bf16, XOR-swizzled
//  [64K,80K) lS                            S tile  [128][64] bf16, wave-private rows
// Swizzle: element (r,c) -> byte r*rowB + ((2c) ^ ((r&7)<<4)). Same formula on
// every reader/writer of a tile -> consistent.

__global__ __launch_bounds__(NTHREADS, 4)
void attn_relu15_kernel(const float* __restrict__ q, const float* __restrict__ k,
                        const float* __restrict__ v, const int* __restrict__ mask,
                        float* __restrict__ outp, float* __restrict__ attnp)
{
  // XCD-grouped bijective mapping: a head's 8 q-tiles share one XCD's L2.
  const int blk = blockIdx.x;
  const int bh  = (blk & 7) * 8 + (blk >> 6);   // 0..63
  const int qt  = (blk >> 3) & 7;               // 0..7
  const int b   = bh >> 4;

  const int tid  = threadIdx.x;
  const int lane = tid & 63;
  const int wq   = tid >> 6;          // wave 0..7 owns q-rows [16wq, 16wq+16)
  const int lhi  = lane >> 4;         // 0..3
  const int llo  = lane & 15;

  __shared__ __align__(16) char smem[81920];
  char* const lK0 = smem;
  char* const lV0 = smem + 32768;
  char* const lS  = smem + 65536;

  const float* qg = q + (size_t)bh * (S_ * D_) + (size_t)qt * BM * D_;
  const float* kg = k + (size_t)bh * (S_ * D_);
  const float* vg = v + (size_t)bh * (S_ * D_);
  const int*   mg = mask  + (size_t)b * S_ * S_ + (size_t)qt * BM * S_;
  float*       ag = attnp + (size_t)bh * S_ * S_ + (size_t)qt * BM * S_;
  float*       og = outp  + (size_t)bh * (S_ * D_) + (size_t)qt * BM * D_;

  const float invT = 0.08838834764831843f;   // 1/sqrt(128)

  // ---- Q fragments straight into registers (scaled, bf16), loaded once ----
  // Per instruction the wave covers 16 rows x 128B contiguous: coalesced.
  s16x8 qf[4];
  {
    const float* qrow = qg + (size_t)(16 * wq + llo) * D_;
    #pragma unroll
    for (int ks = 0; ks < 4; ++ks) {
      int d0 = 32 * ks + 8 * lhi;
      f32x4 x0 = *(const f32x4*)(qrow + d0);
      f32x4 x1 = *(const f32x4*)(qrow + d0 + 4);
      s16x8 h;
      h[0]=f2bf(x0[0]*invT); h[1]=f2bf(x0[1]*invT); h[2]=f2bf(x0[2]*invT); h[3]=f2bf(x0[3]*invT);
      h[4]=f2bf(x1[0]*invT); h[5]=f2bf(x1[1]*invT); h[6]=f2bf(x1[2]*invT); h[7]=f2bf(x1[3]*invT);
      qf[ks] = h;
    }
  }

  // ---- prologue: stage K/V tile 0 into buffer 0 ----
  {
    #pragma unroll
    for (int rep = 0; rep < 4; ++rep) {
      int flat = (tid + NTHREADS * rep) * 4;       // 64*128 elems
      int r = flat >> 7, c = flat & 127;
      f32x4 x = *(const f32x4*)(kg + flat);
      s16x4 h; h[0]=f2bf(x[0]); h[1]=f2bf(x[1]); h[2]=f2bf(x[2]); h[3]=f2bf(x[3]);
      *(s16x4*)(lK0 + r * 256 + ((c * 2) ^ ((r & 7) << 4))) = h;
    }
    #pragma unroll
    for (int rep = 0; rep < 4; ++rep) {            // 4x4 quad-shuffle transpose
      int bid = (tid >> 2) + 128 * rep;            // 512 blocks: 16(k) x 32(d)
      int kb = bid >> 5, db = bid & 31, l2 = lane & 3;
      f32x4 x = *(const f32x4*)(vg + (size_t)(kb * 4 + l2) * D_ + db * 4);
      float v0=x[0], v1=x[1], v2=x[2], v3=x[3], t;
      t=(l2&1)?v0:v1; t=__shfl_xor(t,1); if(l2&1)v0=t; else v1=t;
      t=(l2&1)?v2:v3; t=__shfl_xor(t,1); if(l2&1)v2=t; else v3=t;
      t=(l2&2)?v0:v2; t=__shfl_xor(t,2); if(l2&2)v0=t; else v2=t;
      t=(l2&2)?v1:v3; t=__shfl_xor(t,2); if(l2&2)v1=t; else v3=t;
      int dd = db * 4 + l2;
      s16x4 h; h[0]=f2bf(v0); h[1]=f2bf(v1); h[2]=f2bf(v2); h[3]=f2bf(v3);
      *(s16x4*)(lV0 + dd * 128 + ((kb * 8) ^ ((dd & 7) << 4))) = h;
    }
  }
  __syncthreads();

  f32x4 oacc[8];
  #pragma unroll
  for (int i = 0; i < 8; ++i) oacc[i] = (f32x4){0.f,0.f,0.f,0.f};

  int cur = 0;
  for (int kt = 0; kt < NKT; ++kt) {
    const bool pf = (kt + 1 < NKT);

    // ---- issue next K-tile loads early (T14: HBM latency hides under QK) ----
    f32x4 kst[4];
    const float* kgt = kg + (size_t)(kt + 1) * BN * D_;
    if (pf) {
      #pragma unroll
      for (int rep = 0; rep < 4; ++rep)
        kst[rep] = *(const f32x4*)(kgt + (tid + NTHREADS * rep) * 4);
    }

    // ---- QK^T: each wave 16 q-rows x 64 k-cols ----
    char* lKc = lK0 + cur * 16384;
    f32x4 sacc[4];
    #pragma unroll
    for (int i = 0; i < 4; ++i) sacc[i] = (f32x4){0.f,0.f,0.f,0.f};
    #pragma unroll
    for (int ks = 0; ks < 4; ++ks) {
      s16x8 bfr[4];
      #pragma unroll
      for (int nt = 0; nt < 4; ++nt) {
        int kr = 16 * nt + llo;
        bfr[nt] = *(s16x8*)(lKc + kr * 256 + ((64 * ks + 16 * lhi) ^ ((kr & 7) << 4)));
      }
      #pragma unroll
      for (int nt = 0; nt < 4; ++nt)
        sacc[nt] = __builtin_amdgcn_mfma_f32_16x16x32_bf16(qf[ks], bfr[nt], sacc[nt], 0, 0, 0);
    }

    // ---- drain+write staged K into the other buffer; issue V loads ----
    // (other buffer was last read in iter kt-1; barrier at end of kt-1 makes
    //  writing it here safe -> only ONE barrier per iteration needed)
    f32x4 vst[4];
    const float* vgt = vg + (size_t)(kt + 1) * BN * D_;
    if (pf) {
      char* lKn = lK0 + (cur ^ 1) * 16384;
      #pragma unroll
      for (int rep = 0; rep < 4; ++rep) {
        int flat = (tid + NTHREADS * rep) * 4;
        int r = flat >> 7, c = flat & 127;
        f32x4 x = kst[rep];
        s16x4 h; h[0]=f2bf(x[0]); h[1]=f2bf(x[1]); h[2]=f2bf(x[2]); h[3]=f2bf(x[3]);
        *(s16x4*)(lKn + r * 256 + ((c * 2) ^ ((r & 7) << 4))) = h;
      }
      #pragma unroll
      for (int rep = 0; rep < 4; ++rep) {
        int bid = (tid >> 2) + 128 * rep;
        int kb = bid >> 5, db = bid & 31, l2 = lane & 3;
        vst[rep] = *(const f32x4*)(vgt + (size_t)(kb * 4 + l2) * D_ + db * 4);
      }
    }

    // ---- clip -> bf16 -> lS (wave-private rows: no cross-wave sync) ----
    #pragma unroll
    for (int nt = 0; nt < 4; ++nt) {
      int c = 16 * nt + llo;
      #pragma unroll
      for (int j = 0; j < 4; ++j) {
        int r = 16 * wq + 4 * lhi + j;
        float val = fminf(fmaxf(sacc[nt][j], 0.f), 15.f);
        *(uint16_t*)(lS + r * 128 + ((c * 2) ^ ((r & 7) << 4))) = f2bf(val);
      }
    }
    // ---- mask + coalesced attn stream + masked write-back (same wave) ----
    #pragma unroll
    for (int rep = 0; rep < 4; ++rep) {
      int flat = (lane + 64 * rep) * 4;            // 16x64 wave region
      int lr = flat >> 6, c = flat & 63;
      int r = 16 * wq + lr;
      char* sb = lS + r * 128 + ((c * 2) ^ ((r & 7) << 4));
      s16x4 sv = *(s16x4*)sb;
      i32x4 m = *(const i32x4*)(mg + (size_t)r * S_ + kt * BN + c);
      f32x4 a;
      #pragma unroll
      for (int i = 0; i < 4; ++i) {
        if (m[i] == 0) sv[i] = 0;
        a[i] = bf2f((uint16_t)sv[i]);
      }
      __builtin_nontemporal_store(a, (f32x4*)(ag + (size_t)r * S_ + kt * BN + c));
      *(s16x4*)sb = sv;
    }

    // ---- PV: O[16 x 128] += S @ V^T-tile ----
    char* lVc = lV0 + cur * 16384;
    #pragma unroll
    for (int ks = 0; ks < 2; ++ks) {
      int r = 16 * wq + llo;
      s16x8 saf = *(s16x8*)(lS + r * 128 + ((64 * ks + 16 * lhi) ^ ((r & 7) << 4)));
      #pragma unroll
      for (int nt = 0; nt < 8; ++nt) {
        int dd = 16 * nt + llo;
        s16x8 vb = *(s16x8*)(lVc + dd * 128 + ((64 * ks + 16 * lhi) ^ ((dd & 7) << 4)));
        oacc[nt] = __builtin_amdgcn_mfma_f32_16x16x32_bf16(saf, vb, oacc[nt], 0, 0, 0);
      }
    }

    // ---- transpose + write staged V into the other buffer ----
    if (pf) {
      char* lVn = lV0 + (cur ^ 1) * 16384;
      #pragma unroll
      for (int rep = 0; rep < 4; ++rep) {
        int bid = (tid >> 2) + 128 * rep;
        int kb = bid >> 5, db = bid & 31, l2 = lane & 3;
        f32x4 x = vst[rep];
        float v0=x[0], v1=x[1], v2=x[2], v3=x[3], t;
        t=(l2&1)?v0:v1; t=__shfl_xor(t,1); if(l2&1)v0=t; else v1=t;
        t=(l2&1)?v2:v3; t=__shfl_xor(t,1); if(l2&1)v2=t; else v3=t;
        t=(l2&2)?v0:v2; t=__shfl_xor(t,2); if(l2&2)v0=t; else v2=t;
        t=(l2&2)?v1:v3; t=__shfl_xor(t,2); if(l2&2)v1=t; else v3=t;
        int dd = db * 4 + l2;
        s16x4 h; h[0]=f2bf(v0); h[1]=f2bf(v1); h[2]=f2bf(v2); h[3]=f2bf(v3);
        *(s16x4*)(lVn + dd * 128 + ((kb * 8) ^ ((dd & 7) << 4))) = h;
      }
    }

    __syncthreads();   // the ONE barrier per K-tile
    cur ^= 1;
  }

  // ---- epilogue: coalesced O store via LDS bounce (reuses lK/lV space;
  //      loop's final barrier already separates us from all PV reads) ----
  {
    char* lOw = smem + wq * 8192;     // [16][128] f32, wave-private, swizzled
    #pragma unroll
    for (int nt = 0; nt < 8; ++nt) {
      int c = 16 * nt + llo;
      #pragma unroll
      for (int j = 0; j < 4; ++j) {
        int lr = 4 * lhi + j;
        *(float*)(lOw + lr * 512 + ((c * 4) ^ ((lr & 7) << 4))) = oacc[nt][j];
      }
    }
    #pragma unroll
    for (int rep = 0; rep < 8; ++rep) {
      int flat = (lane + 64 * rep) * 4;
      int lr = flat >> 7, c = flat & 127;
      f32x4 x = *(f32x4*)(lOw + lr * 512 + ((c * 4) ^ ((lr & 7) << 4)));
      __builtin_nontemporal_store(x, (f32x4*)(og + wq * 2048 + flat));
    }
  }
}

extern "C" void kernel_launch(void* const* d_in, const int* in_sizes, int n_in,
                              void* d_out, int out_size, void* d_ws, size_t ws_size,
                              hipStream_t stream) {
  const float* q    = (const float*)d_in[0];
  const float* k    = (const float*)d_in[1];
  const float* v    = (const float*)d_in[2];
  const int*   mask = (const int*)d_in[3];
  float* outp  = (float*)d_out;
  float* attnp = outp + (size_t)B_ * H_ * S_ * D_;   // tuple: (out, attn) concat
  dim3 grid(B_ * H_ * (S_ / BM));                    // 512 blocks
  attn_relu15_kernel<<<grid, NTHREADS, 0, stream>>>(q, k, v, mask, outp, attnp);
}

// Round 3
// 172.602 us; speedup vs baseline: 1.5203x; 1.5203x over previous
//
#include <hip/hip_runtime.h>
#include <stdint.h>

// Shapes (fixed for this problem)
#define B_   4
#define H_   16
#define S_   1024
#define D_   128
#define BM   64                  // Q rows per block
#define BN   32                  // K/V rows per iteration
#define NKT  (S_ / BN)           // 32
#define NTHREADS 256             // 4 waves; each wave owns 16 q-rows

typedef float f32x4 __attribute__((ext_vector_type(4)));
typedef short s16x8 __attribute__((ext_vector_type(8)));   // 8 bf16 (MFMA A/B frag)
typedef short s16x4 __attribute__((ext_vector_type(4)));

static __device__ __forceinline__ uint16_t f2bf(float f) {
  uint32_t u = __float_as_uint(f);
  u += 0x7FFFu + ((u >> 16) & 1u);          // round-to-nearest-even
  return (uint16_t)(u >> 16);
}

// LDS map: 40960 B/block -> 4 blocks/CU = 160 KB exactly (16 waves/CU).
//  [    0,16384) lK dbuf: [32][128] bf16, row 256B, XOR swizzle ((r&7)<<4)
//  [16384,36864) lV dbuf: V^T [128][BN] bf16, row stride 80B (pad: 2-way reads)
//  [36864,40960) lS:      [64][32] bf16, row 64B, XOR swizzle ((r&3)<<4)

__global__ __launch_bounds__(NTHREADS, 4)   // 4 blocks/CU -> 128 VGPR budget
void attn_relu15_kernel(const float* __restrict__ q, const float* __restrict__ k,
                        const float* __restrict__ v, const int* __restrict__ mask,
                        float* __restrict__ outp, float* __restrict__ attnp)
{
  // XCD-grouped bijective mapping (1024 = 8 XCD * 128): the 16 q-tiles of a
  // head are consecutive on one XCD -> its K/V stays hot in that XCD's L2.
  const int blk = blockIdx.x;
  const int g   = (blk & 7) * 128 + (blk >> 3);
  const int bh  = g >> 4;              // 0..63
  const int qt  = g & 15;              // 0..15
  const int b   = bh >> 4;

  const int tid  = threadIdx.x;
  const int lane = tid & 63;
  const int wq   = tid >> 6;           // wave 0..3 owns q-rows [16wq, 16wq+16)
  const int lhi  = lane >> 4;          // 0..3
  const int llo  = lane & 15;

  __shared__ __align__(16) char smem[40960];

  const float* qg = q + (size_t)bh * (S_ * D_) + (size_t)qt * BM * D_;
  const float* kg = k + (size_t)bh * (S_ * D_);
  const float* vg = v + (size_t)bh * (S_ * D_);
  const int*   mg = mask  + (size_t)b * S_ * S_ + (size_t)qt * BM * S_;
  float*       ag = attnp + (size_t)bh * S_ * S_ + (size_t)qt * BM * S_;
  float*       og = outp  + (size_t)bh * (S_ * D_) + (size_t)qt * BM * D_;

  const float invT = 0.08838834764831843f;   // 1/sqrt(128)

  // ---- Q fragments into registers (scaled, bf16), loaded once ----
  s16x8 qf[4];
  {
    const float* qrow = qg + (size_t)(16 * wq + llo) * D_;
    #pragma unroll
    for (int ks = 0; ks < 4; ++ks) {
      int d0 = 32 * ks + 8 * lhi;
      f32x4 x0 = *(const f32x4*)(qrow + d0);
      f32x4 x1 = *(const f32x4*)(qrow + d0 + 4);
      s16x8 h;
      h[0]=f2bf(x0[0]*invT); h[1]=f2bf(x0[1]*invT); h[2]=f2bf(x0[2]*invT); h[3]=f2bf(x0[3]*invT);
      h[4]=f2bf(x1[0]*invT); h[5]=f2bf(x1[1]*invT); h[6]=f2bf(x1[2]*invT); h[7]=f2bf(x1[3]*invT);
      qf[ks] = h;
    }
  }

  // ---- prologue: stage K/V tile 0 into buffer 0 ----
  {
    #pragma unroll
    for (int rep = 0; rep < 4; ++rep) {                 // K: 32x128 f32 -> bf16
      int flat = (tid + NTHREADS * rep) * 4;
      int r = flat >> 7, c = flat & 127;
      f32x4 x = *(const f32x4*)(kg + flat);
      s16x4 h; h[0]=f2bf(x[0]); h[1]=f2bf(x[1]); h[2]=f2bf(x[2]); h[3]=f2bf(x[3]);
      *(s16x4*)(smem + r * 256 + ((c * 2) ^ ((r & 7) << 4))) = h;
    }
    #pragma unroll
    for (int rep = 0; rep < 4; ++rep) {                 // V: 4x4 quad transpose
      int bid = (tid >> 2) + 64 * rep;                  // 256 blocks: 8(k) x 32(d)
      int kb = bid >> 5, db = bid & 31, l2 = lane & 3;
      f32x4 x = *(const f32x4*)(vg + (size_t)(kb * 4 + l2) * D_ + db * 4);
      float v0=x[0], v1=x[1], v2=x[2], v3=x[3], t;
      t=(l2&1)?v0:v1; t=__shfl_xor(t,1); if(l2&1)v0=t; else v1=t;
      t=(l2&1)?v2:v3; t=__shfl_xor(t,1); if(l2&1)v2=t; else v3=t;
      t=(l2&2)?v0:v2; t=__shfl_xor(t,2); if(l2&2)v0=t; else v2=t;
      t=(l2&2)?v1:v3; t=__shfl_xor(t,2); if(l2&2)v1=t; else v3=t;
      int dd = db * 4 + l2;
      s16x4 h; h[0]=f2bf(v0); h[1]=f2bf(v1); h[2]=f2bf(v2); h[3]=f2bf(v3);
      *(s16x4*)(smem + 16384 + dd * 80 + kb * 8) = h;
    }
  }
  __syncthreads();

  f32x4 oacc[8];
  #pragma unroll
  for (int i = 0; i < 8; ++i) oacc[i] = (f32x4){0.f,0.f,0.f,0.f};

  int cur = 0;
  for (int kt = 0; kt < NKT; ++kt) {
    const bool pf = (kt + 1 < NKT);
    char* lKc = smem + cur * 8192;
    char* lVc = smem + 16384 + cur * 10240;
    char* lS  = smem + 36864;

    // ---- issue next K-tile loads early (latency hides under QK) ----
    f32x4 kst[4];
    const float* kgt = kg + (size_t)(kt + 1) * BN * D_;
    if (pf) {
      #pragma unroll
      for (int rep = 0; rep < 4; ++rep)
        kst[rep] = *(const f32x4*)(kgt + (tid + NTHREADS * rep) * 4);
    }
    // ---- issue this tile's mask loads (consumed after QK) ----
    int mreg[8];
    #pragma unroll
    for (int nt = 0; nt < 2; ++nt)
      #pragma unroll
      for (int j = 0; j < 4; ++j)
        mreg[nt * 4 + j] =
          mg[(size_t)(16 * wq + 4 * lhi + j) * S_ + kt * BN + 16 * nt + llo];

    // ---- QK^T: 16 q-rows x 32 k-cols per wave ----
    f32x4 sacc[2];
    sacc[0] = (f32x4){0.f,0.f,0.f,0.f}; sacc[1] = sacc[0];
    #pragma unroll
    for (int ks = 0; ks < 4; ++ks) {
      s16x8 bfr[2];
      #pragma unroll
      for (int nt = 0; nt < 2; ++nt) {
        int kr = 16 * nt + llo;
        bfr[nt] = *(s16x8*)(lKc + kr * 256 + ((64 * ks + 16 * lhi) ^ ((kr & 7) << 4)));
      }
      #pragma unroll
      for (int nt = 0; nt < 2; ++nt)
        sacc[nt] = __builtin_amdgcn_mfma_f32_16x16x32_bf16(qf[ks], bfr[nt], sacc[nt], 0, 0, 0);
    }

    // ---- write staged K into other buffer; issue V loads ----
    f32x4 vst[4];
    const float* vgt = vg + (size_t)(kt + 1) * BN * D_;
    if (pf) {
      char* lKn = smem + (cur ^ 1) * 8192;
      #pragma unroll
      for (int rep = 0; rep < 4; ++rep) {
        int flat = (tid + NTHREADS * rep) * 4;
        int r = flat >> 7, c = flat & 127;
        f32x4 x = kst[rep];
        s16x4 h; h[0]=f2bf(x[0]); h[1]=f2bf(x[1]); h[2]=f2bf(x[2]); h[3]=f2bf(x[3]);
        *(s16x4*)(lKn + r * 256 + ((c * 2) ^ ((r & 7) << 4))) = h;
      }
      #pragma unroll
      for (int rep = 0; rep < 4; ++rep) {
        int bid = (tid >> 2) + 64 * rep;
        int kb = bid >> 5, db = bid & 31, l2 = lane & 3;
        vst[rep] = *(const f32x4*)(vgt + (size_t)(kb * 4 + l2) * D_ + db * 4);
      }
    }

    // ---- clip + mask directly from sacc: attn f32 store + S->lS bf16 ----
    #pragma unroll
    for (int nt = 0; nt < 2; ++nt) {
      int c = 16 * nt + llo;
      #pragma unroll
      for (int j = 0; j < 4; ++j) {
        int r = 16 * wq + 4 * lhi + j;
        float val = fminf(fmaxf(sacc[nt][j], 0.f), 15.f);
        if (mreg[nt * 4 + j] == 0) val = 0.f;
        __builtin_nontemporal_store(val, ag + (size_t)r * S_ + kt * BN + c);
        *(uint16_t*)(lS + r * 64 + ((c * 2) ^ ((r & 3) << 4))) = f2bf(val);
      }
    }

    // ---- PV: O[16 x 128] += S @ V^T (single K=32 step) ----
    {
      int r = 16 * wq + llo;
      s16x8 saf = *(s16x8*)(lS + r * 64 + ((16 * lhi) ^ ((r & 3) << 4)));
      #pragma unroll
      for (int nt = 0; nt < 8; ++nt) {
        int dd = 16 * nt + llo;
        s16x8 vb = *(s16x8*)(lVc + dd * 80 + 16 * lhi);
        oacc[nt] = __builtin_amdgcn_mfma_f32_16x16x32_bf16(saf, vb, oacc[nt], 0, 0, 0);
      }
    }

    // ---- transpose + write staged V into other buffer ----
    if (pf) {
      char* lVn = smem + 16384 + (cur ^ 1) * 10240;
      #pragma unroll
      for (int rep = 0; rep < 4; ++rep) {
        int bid = (tid >> 2) + 64 * rep;
        int kb = bid >> 5, db = bid & 31, l2 = lane & 3;
        f32x4 x = vst[rep];
        float v0=x[0], v1=x[1], v2=x[2], v3=x[3], t;
        t=(l2&1)?v0:v1; t=__shfl_xor(t,1); if(l2&1)v0=t; else v1=t;
        t=(l2&1)?v2:v3; t=__shfl_xor(t,1); if(l2&1)v2=t; else v3=t;
        t=(l2&2)?v0:v2; t=__shfl_xor(t,2); if(l2&2)v0=t; else v2=t;
        t=(l2&2)?v1:v3; t=__shfl_xor(t,2); if(l2&2)v1=t; else v3=t;
        int dd = db * 4 + l2;
        s16x4 h; h[0]=f2bf(v0); h[1]=f2bf(v1); h[2]=f2bf(v2); h[3]=f2bf(v3);
        *(s16x4*)(lVn + dd * 80 + kb * 8) = h;
      }
    }

    __syncthreads();   // the ONE barrier per K-tile
    cur ^= 1;
  }

  // ---- epilogue: O store (64B-segment coalesced, pure stream) ----
  #pragma unroll
  for (int nt = 0; nt < 8; ++nt) {
    int n = 16 * nt + llo;
    #pragma unroll
    for (int j = 0; j < 4; ++j) {
      int m = 16 * wq + 4 * lhi + j;
      __builtin_nontemporal_store(oacc[nt][j], og + (size_t)m * D_ + n);
    }
  }
}

extern "C" void kernel_launch(void* const* d_in, const int* in_sizes, int n_in,
                              void* d_out, int out_size, void* d_ws, size_t ws_size,
                              hipStream_t stream) {
  const float* q    = (const float*)d_in[0];
  const float* k    = (const float*)d_in[1];
  const float* v    = (const float*)d_in[2];
  const int*   mask = (const int*)d_in[3];
  float* outp  = (float*)d_out;
  float* attnp = outp + (size_t)B_ * H_ * S_ * D_;   // tuple: (out, attn) concat
  dim3 grid(B_ * H_ * (S_ / BM));                    // 1024 blocks
  attn_relu15_kernel<<<grid, NTHREADS, 0, stream>>>(q, k, v, mask, outp, attnp);
}

// Round 4
// 134.567 us; speedup vs baseline: 1.9500x; 1.2826x over previous
//
#include <hip/hip_runtime.h>
#include <stdint.h>

// Shapes (fixed for this problem)
#define B_   4
#define H_   16
#define S_   1024
#define D_   128
#define BM   64                  // Q rows per block
#define BN   32                  // K/V rows per iteration
#define NKT  (S_ / BN)           // 32
#define NTHREADS 256             // 4 waves; each wave owns 16 q-rows

typedef float f32x4 __attribute__((ext_vector_type(4)));
typedef short s16x8 __attribute__((ext_vector_type(8)));   // 8 bf16 (MFMA A/B frag)
typedef short s16x4 __attribute__((ext_vector_type(4)));

static __device__ __forceinline__ uint16_t f2bf(float f) {
  uint32_t u = __float_as_uint(f);
  u += 0x7FFFu + ((u >> 16) & 1u);          // round-to-nearest-even
  return (uint16_t)(u >> 16);
}

// LDS-only barrier (T4): do NOT drain vmcnt (attn/O streaming stores stay in
// flight across the barrier). lgkmcnt(0) makes all ds_writes visible; the
// sched_barrier stops the compiler hoisting post-barrier LDS reads (rule #18).
#define LDS_BARRIER() do {                                   \
    asm volatile("s_waitcnt lgkmcnt(0)" ::: "memory");       \
    __builtin_amdgcn_s_barrier();                            \
    __builtin_amdgcn_sched_barrier(0);                       \
  } while (0)

// LDS map (36864 B -> 4 blocks/CU, 16 waves/CU):
//  [    0,16384) lK dbuf: fragment-major, chunk16B[(ks*2+nt)*64 + lane]
//  [16384,32768) lV dbuf: fragment-major, chunk16B[nt*64 + lane]
//  [32768,36864) lS:      fragment-major per wave, chunk16B[wq*64 + lane]
// Every MFMA-operand ds_read_b128 is base + lane*16 -> contiguous 1KB,
// conflict-free. K's LDS write is linear (o = tid*8) with the global source
// address inverse-swizzled (m173 pattern).

__global__ __launch_bounds__(NTHREADS, 2)   // cap 256 VGPR; natural ~120, no squeeze
void attn_relu15_kernel(const float* __restrict__ q, const float* __restrict__ k,
                        const float* __restrict__ v, const int* __restrict__ mask,
                        float* __restrict__ outp, float* __restrict__ attnp)
{
  // XCD-grouped bijective mapping (1024 = 8 XCD * 128): the 16 q-tiles of a
  // head are consecutive on one XCD -> its K/V stays hot in that XCD's L2.
  const int blk = blockIdx.x;
  const int g   = (blk & 7) * 128 + (blk >> 3);
  const int bh  = g >> 4;              // 0..63
  const int qt  = g & 15;              // 0..15
  const int b   = bh >> 4;

  const int tid  = threadIdx.x;
  const int lane = tid & 63;
  const int wq   = tid >> 6;           // wave 0..3 owns q-rows [16wq, 16wq+16)
  const int lhi  = lane >> 4;          // 0..3
  const int llo  = lane & 15;

  __shared__ __align__(16) char smem[36864];
  char* const lK0 = smem;
  char* const lV0 = smem + 16384;
  char* const lS  = smem + 32768 + wq * 1024;

  const float* qg = q + (size_t)bh * (S_ * D_) + (size_t)qt * BM * D_;
  const float* kg = k + (size_t)bh * (S_ * D_);
  const float* vg = v + (size_t)bh * (S_ * D_);
  const int*   mg = mask  + (size_t)b * S_ * S_ + (size_t)qt * BM * S_;
  float*       ag = attnp + (size_t)bh * S_ * S_ + (size_t)qt * BM * S_;
  float*       og = outp  + (size_t)bh * (S_ * D_) + (size_t)qt * BM * D_;

  const float invT = 0.08838834764831843f;   // 1/sqrt(128)

  // K-staging index helper: linear LDS offset o -> (row, col) in the K tile.
  // o = chunk*16 + half*8; chunk = ((ks*2+nt)*4+lhi)*16+llo holds
  // K[16nt+llo][32ks+8lhi .. +7].
  #define K_O(rep)   ((tid + NTHREADS * (rep)) * 8)
  #define K_ROW(o)   ((((o) >> 10) & 1) * 16 + (((o) >> 4) & 15))
  #define K_COL(o)   (((o) >> 11) * 32 + (((o) >> 8) & 3) * 8 + (((o) >> 3) & 1) * 4)

  // ---- Q fragments into registers (scaled, bf16), loaded once ----
  s16x8 qf[4];
  {
    const float* qrow = qg + (size_t)(16 * wq + llo) * D_;
    #pragma unroll
    for (int ks = 0; ks < 4; ++ks) {
      int d0 = 32 * ks + 8 * lhi;
      f32x4 x0 = *(const f32x4*)(qrow + d0);
      f32x4 x1 = *(const f32x4*)(qrow + d0 + 4);
      s16x8 h;
      h[0]=f2bf(x0[0]*invT); h[1]=f2bf(x0[1]*invT); h[2]=f2bf(x0[2]*invT); h[3]=f2bf(x0[3]*invT);
      h[4]=f2bf(x1[0]*invT); h[5]=f2bf(x1[1]*invT); h[6]=f2bf(x1[2]*invT); h[7]=f2bf(x1[3]*invT);
      qf[ks] = h;
    }
  }

  // ---- prologue: stage K/V tile 0 into buffer 0 ----
  {
    #pragma unroll
    for (int rep = 0; rep < 4; ++rep) {           // K: pre-swizzled src, linear dst
      int o = K_O(rep);
      f32x4 x = *(const f32x4*)(kg + K_ROW(o) * D_ + K_COL(o));
      s16x4 h; h[0]=f2bf(x[0]); h[1]=f2bf(x[1]); h[2]=f2bf(x[2]); h[3]=f2bf(x[3]);
      *(s16x4*)(lK0 + o) = h;
    }
    #pragma unroll
    for (int rep = 0; rep < 4; ++rep) {           // V: 4x4 quad transpose
      int bid = (tid >> 2) + 64 * rep;            // 256 blocks: 8(k) x 32(d)
      int kb = bid >> 5, db = bid & 31, l2 = lane & 3;
      f32x4 x = *(const f32x4*)(vg + (size_t)(kb * 4 + l2) * D_ + db * 4);
      float v0=x[0], v1=x[1], v2=x[2], v3=x[3], t;
      t=(l2&1)?v0:v1; t=__shfl_xor(t,1); if(l2&1)v0=t; else v1=t;
      t=(l2&1)?v2:v3; t=__shfl_xor(t,1); if(l2&1)v2=t; else v3=t;
      t=(l2&2)?v0:v2; t=__shfl_xor(t,2); if(l2&2)v0=t; else v2=t;
      t=(l2&2)?v1:v3; t=__shfl_xor(t,2); if(l2&2)v1=t; else v3=t;
      int dd = db * 4 + l2;
      s16x4 h; h[0]=f2bf(v0); h[1]=f2bf(v1); h[2]=f2bf(v2); h[3]=f2bf(v3);
      *(s16x4*)(lV0 + (dd >> 4) * 1024 + ((kb >> 1) & 3) * 256
                    + (dd & 15) * 16 + (kb & 1) * 8) = h;
    }
  }
  LDS_BARRIER();

  f32x4 oacc[8];
  #pragma unroll
  for (int i = 0; i < 8; ++i) oacc[i] = (f32x4){0.f,0.f,0.f,0.f};

  int cur = 0;
  for (int kt = 0; kt < NKT; ++kt) {
    const bool pf = (kt + 1 < NKT);
    char* lKc = lK0 + cur * 8192;
    char* lVc = lV0 + cur * 8192;

    // ---- issue next K-tile loads early (latency hides under QK) ----
    f32x4 kst[4];
    const float* kgt = kg + (size_t)(kt + 1) * BN * D_;
    if (pf) {
      #pragma unroll
      for (int rep = 0; rep < 4; ++rep) {
        int o = K_O(rep);
        kst[rep] = *(const f32x4*)(kgt + K_ROW(o) * D_ + K_COL(o));
      }
    }
    // ---- issue this tile's mask loads (consumed after QK) ----
    int mreg[8];
    #pragma unroll
    for (int nt = 0; nt < 2; ++nt)
      #pragma unroll
      for (int j = 0; j < 4; ++j)
        mreg[nt * 4 + j] =
          mg[(size_t)(16 * wq + 4 * lhi + j) * S_ + kt * BN + 16 * nt + llo];

    // ---- QK^T: 16 q-rows x 32 k-cols per wave ----
    f32x4 sacc[2];
    sacc[0] = (f32x4){0.f,0.f,0.f,0.f}; sacc[1] = sacc[0];
    #pragma unroll
    for (int ks = 0; ks < 4; ++ks) {
      s16x8 bfr[2];
      #pragma unroll
      for (int nt = 0; nt < 2; ++nt)
        bfr[nt] = *(s16x8*)(lKc + (ks * 2 + nt) * 1024 + lane * 16);
      #pragma unroll
      for (int nt = 0; nt < 2; ++nt)
        sacc[nt] = __builtin_amdgcn_mfma_f32_16x16x32_bf16(qf[ks], bfr[nt], sacc[nt], 0, 0, 0);
    }

    // ---- write staged K into other buffer; issue V loads ----
    f32x4 vst[4];
    const float* vgt = vg + (size_t)(kt + 1) * BN * D_;
    if (pf) {
      char* lKn = lK0 + (cur ^ 1) * 8192;
      #pragma unroll
      for (int rep = 0; rep < 4; ++rep) {
        f32x4 x = kst[rep];
        s16x4 h; h[0]=f2bf(x[0]); h[1]=f2bf(x[1]); h[2]=f2bf(x[2]); h[3]=f2bf(x[3]);
        *(s16x4*)(lKn + K_O(rep)) = h;
      }
      #pragma unroll
      for (int rep = 0; rep < 4; ++rep) {
        int bid = (tid >> 2) + 64 * rep;
        int kb = bid >> 5, db = bid & 31, l2 = lane & 3;
        vst[rep] = *(const f32x4*)(vgt + (size_t)(kb * 4 + l2) * D_ + db * 4);
      }
    }

    // ---- clip + mask from sacc: attn f32 stream + S->lS (fragment-major) ----
    #pragma unroll
    for (int nt = 0; nt < 2; ++nt) {
      int c = 16 * nt + llo;
      char* sb = lS + (2 * nt + (llo >> 3)) * 256 + (llo & 7) * 2;
      #pragma unroll
      for (int j = 0; j < 4; ++j) {
        int r = 16 * wq + 4 * lhi + j;
        float val = fminf(fmaxf(sacc[nt][j], 0.f), 15.f);
        if (mreg[nt * 4 + j] == 0) val = 0.f;
        __builtin_nontemporal_store(val, ag + (size_t)r * S_ + kt * BN + c);
        *(uint16_t*)(sb + (4 * lhi + j) * 16) = f2bf(val);
      }
    }

    // ---- PV: O[16 x 128] += S @ V^T (single K=32 step) ----
    {
      s16x8 saf = *(s16x8*)(lS + lane * 16);
      #pragma unroll
      for (int nt = 0; nt < 8; ++nt) {
        s16x8 vb = *(s16x8*)(lVc + nt * 1024 + lane * 16);
        oacc[nt] = __builtin_amdgcn_mfma_f32_16x16x32_bf16(saf, vb, oacc[nt], 0, 0, 0);
      }
    }

    // ---- transpose + write staged V into other buffer ----
    if (pf) {
      char* lVn = lV0 + (cur ^ 1) * 8192;
      #pragma unroll
      for (int rep = 0; rep < 4; ++rep) {
        int bid = (tid >> 2) + 64 * rep;
        int kb = bid >> 5, db = bid & 31, l2 = lane & 3;
        f32x4 x = vst[rep];
        float v0=x[0], v1=x[1], v2=x[2], v3=x[3], t;
        t=(l2&1)?v0:v1; t=__shfl_xor(t,1); if(l2&1)v0=t; else v1=t;
        t=(l2&1)?v2:v3; t=__shfl_xor(t,1); if(l2&1)v2=t; else v3=t;
        t=(l2&2)?v0:v2; t=__shfl_xor(t,2); if(l2&2)v0=t; else v2=t;
        t=(l2&2)?v1:v3; t=__shfl_xor(t,2); if(l2&2)v1=t; else v3=t;
        int dd = db * 4 + l2;
        s16x4 h; h[0]=f2bf(v0); h[1]=f2bf(v1); h[2]=f2bf(v2); h[3]=f2bf(v3);
        *(s16x4*)(lVn + (dd >> 4) * 1024 + ((kb >> 1) & 3) * 256
                      + (dd & 15) * 16 + (kb & 1) * 8) = h;
      }
    }

    LDS_BARRIER();   // the ONE barrier per K-tile; vmcnt never drained
    cur ^= 1;
  }

  // ---- epilogue: O store (64B-segment coalesced, pure stream) ----
  #pragma unroll
  for (int nt = 0; nt < 8; ++nt) {
    int n = 16 * nt + llo;
    #pragma unroll
    for (int j = 0; j < 4; ++j) {
      int m = 16 * wq + 4 * lhi + j;
      __builtin_nontemporal_store(oacc[nt][j], og + (size_t)m * D_ + n);
    }
  }
}

extern "C" void kernel_launch(void* const* d_in, const int* in_sizes, int n_in,
                              void* d_out, int out_size, void* d_ws, size_t ws_size,
                              hipStream_t stream) {
  const float* q    = (const float*)d_in[0];
  const float* k    = (const float*)d_in[1];
  const float* v    = (const float*)d_in[2];
  const int*   mask = (const int*)d_in[3];
  float* outp  = (float*)d_out;
  float* attnp = outp + (size_t)B_ * H_ * S_ * D_;   // tuple: (out, attn) concat
  dim3 grid(B_ * H_ * (S_ / BM));                    // 1024 blocks
  attn_relu15_kernel<<<grid, NTHREADS, 0, stream>>>(q, k, v, mask, outp, attnp);
}

// Round 5
// 125.876 us; speedup vs baseline: 2.0847x; 1.0690x over previous
//
#include <hip/hip_runtime.h>
#include <stdint.h>

// Shapes (fixed for this problem)
#define B_   4
#define H_   16
#define S_   1024
#define D_   128
#define BM   64                  // Q rows per block
#define BN   32                  // K/V rows per iteration
#define NKT  (S_ / BN)           // 32
#define NTHREADS 256             // 4 waves; each wave owns 16 q-rows

typedef float f32x4 __attribute__((ext_vector_type(4)));
typedef short s16x8 __attribute__((ext_vector_type(8)));   // 8 bf16 (MFMA A/B frag)
typedef short s16x4 __attribute__((ext_vector_type(4)));

static __device__ __forceinline__ uint16_t f2bf(float f) {
  uint32_t u = __float_as_uint(f);
  u += 0x7FFFu + ((u >> 16) & 1u);          // round-to-nearest-even
  return (uint16_t)(u >> 16);
}
static __device__ __forceinline__ float bf2f(uint16_t h) {
  return __uint_as_float((uint32_t)h << 16);
}

// LDS-only barrier (T4): do NOT drain vmcnt (attn/O streaming stores stay in
// flight across the barrier). lgkmcnt(0) makes all ds_writes visible; the
// sched_barrier stops the compiler hoisting post-barrier LDS reads (rule #18).
#define LDS_BARRIER() do {                                   \
    asm volatile("s_waitcnt lgkmcnt(0)" ::: "memory");       \
    __builtin_amdgcn_s_barrier();                            \
    __builtin_amdgcn_sched_barrier(0);                       \
  } while (0)

// LDS map (36864 B -> 4 blocks/CU, 16 waves/CU):
//  [    0,16384) lK dbuf: fragment-major, chunk16B[(ks*2+nt)*64 + lane]
//  [16384,32768) lV dbuf: fragment-major, chunk16B[nt*64 + lane]
//  [32768,36864) lS:      per wave 1KB; element (r,c) of the wave's 16x32 tile
//                         at (c>>3)*256 + (r&15)*16 + (c&7)*2
// Every MFMA-operand ds_read_b128 is base + lane*16 -> contiguous 1KB,
// conflict-free. K's LDS write is linear (o = tid*8) with the global source
// address inverse-swizzled (m173 pattern).

__global__ __launch_bounds__(NTHREADS)
__attribute__((amdgpu_waves_per_eu(4, 4)))   // pin 16 waves/CU -> 128 VGPR, no squeeze
void attn_relu15_kernel(const float* __restrict__ q, const float* __restrict__ k,
                        const float* __restrict__ v, const int* __restrict__ mask,
                        float* __restrict__ outp, float* __restrict__ attnp)
{
  // XCD-grouped bijective mapping (1024 = 8 XCD * 128): the 16 q-tiles of a
  // head are consecutive on one XCD -> its K/V stays hot in that XCD's L2.
  const int blk = blockIdx.x;
  const int g   = (blk & 7) * 128 + (blk >> 3);
  const int bh  = g >> 4;              // 0..63
  const int qt  = g & 15;              // 0..15
  const int b   = bh >> 4;

  const int tid  = threadIdx.x;
  const int lane = tid & 63;
  const int wq   = tid >> 6;           // wave 0..3 owns q-rows [16wq, 16wq+16)
  const int lhi  = lane >> 4;          // 0..3
  const int llo  = lane & 15;

  __shared__ __align__(16) char smem[36864];
  char* const lK0 = smem;
  char* const lV0 = smem + 16384;
  char* const lS  = smem + 32768 + wq * 1024;

  const float* qg = q + (size_t)bh * (S_ * D_) + (size_t)qt * BM * D_;
  const float* kg = k + (size_t)bh * (S_ * D_);
  const float* vg = v + (size_t)bh * (S_ * D_);
  const int*   mg = mask  + (size_t)b * S_ * S_ + (size_t)qt * BM * S_;
  float*       ag = attnp + (size_t)bh * S_ * S_ + (size_t)qt * BM * S_;
  float*       og = outp  + (size_t)bh * (S_ * D_) + (size_t)qt * BM * D_;

  const float invT = 0.08838834764831843f;   // 1/sqrt(128)

  // K-staging index helper: linear LDS offset o -> (row, col) in the K tile.
  #define K_O(rep)   ((tid + NTHREADS * (rep)) * 8)
  #define K_ROW(o)   ((((o) >> 10) & 1) * 16 + (((o) >> 4) & 15))
  #define K_COL(o)   (((o) >> 11) * 32 + (((o) >> 8) & 3) * 8 + (((o) >> 3) & 1) * 4)

  // ---- Q fragments into registers (scaled, bf16), loaded once ----
  s16x8 qf[4];
  {
    const float* qrow = qg + (size_t)(16 * wq + llo) * D_;
    #pragma unroll
    for (int ks = 0; ks < 4; ++ks) {
      int d0 = 32 * ks + 8 * lhi;
      f32x4 x0 = *(const f32x4*)(qrow + d0);
      f32x4 x1 = *(const f32x4*)(qrow + d0 + 4);
      s16x8 h;
      h[0]=f2bf(x0[0]*invT); h[1]=f2bf(x0[1]*invT); h[2]=f2bf(x0[2]*invT); h[3]=f2bf(x0[3]*invT);
      h[4]=f2bf(x1[0]*invT); h[5]=f2bf(x1[1]*invT); h[6]=f2bf(x1[2]*invT); h[7]=f2bf(x1[3]*invT);
      qf[ks] = h;
    }
  }

  // ---- prologue: stage K/V tile 0 into buffer 0 ----
  {
    #pragma unroll
    for (int rep = 0; rep < 4; ++rep) {           // K: pre-swizzled src, linear dst
      int o = K_O(rep);
      f32x4 x = *(const f32x4*)(kg + K_ROW(o) * D_ + K_COL(o));
      s16x4 h; h[0]=f2bf(x[0]); h[1]=f2bf(x[1]); h[2]=f2bf(x[2]); h[3]=f2bf(x[3]);
      *(s16x4*)(lK0 + o) = h;
    }
    #pragma unroll
    for (int rep = 0; rep < 4; ++rep) {           // V: 4x4 quad transpose
      int bid = (tid >> 2) + 64 * rep;            // 256 blocks: 8(k) x 32(d)
      int kb = bid >> 5, db = bid & 31, l2 = lane & 3;
      f32x4 x = *(const f32x4*)(vg + (size_t)(kb * 4 + l2) * D_ + db * 4);
      float v0=x[0], v1=x[1], v2=x[2], v3=x[3], t;
      t=(l2&1)?v0:v1; t=__shfl_xor(t,1); if(l2&1)v0=t; else v1=t;
      t=(l2&1)?v2:v3; t=__shfl_xor(t,1); if(l2&1)v2=t; else v3=t;
      t=(l2&2)?v0:v2; t=__shfl_xor(t,2); if(l2&2)v0=t; else v2=t;
      t=(l2&2)?v1:v3; t=__shfl_xor(t,2); if(l2&2)v1=t; else v3=t;
      int dd = db * 4 + l2;
      s16x4 h; h[0]=f2bf(v0); h[1]=f2bf(v1); h[2]=f2bf(v2); h[3]=f2bf(v3);
      *(s16x4*)(lV0 + (dd >> 4) * 1024 + ((kb >> 1) & 3) * 256
                    + (dd & 15) * 16 + (kb & 1) * 8) = h;
    }
  }
  LDS_BARRIER();

  f32x4 oacc[8];
  #pragma unroll
  for (int i = 0; i < 8; ++i) oacc[i] = (f32x4){0.f,0.f,0.f,0.f};

  int cur = 0;
  for (int kt = 0; kt < NKT; ++kt) {
    const bool pf = (kt + 1 < NKT);
    char* lKc = lK0 + cur * 8192;
    char* lVc = lV0 + cur * 8192;

    // ---- issue next K-tile loads early (latency hides under QK) ----
    f32x4 kst[4];
    const float* kgt = kg + (size_t)(kt + 1) * BN * D_;
    if (pf) {
      #pragma unroll
      for (int rep = 0; rep < 4; ++rep) {
        int o = K_O(rep);
        kst[rep] = *(const f32x4*)(kgt + K_ROW(o) * D_ + K_COL(o));
      }
    }
    // ---- issue this tile's mask loads (consumed after QK) ----
    int mreg[8];
    #pragma unroll
    for (int nt = 0; nt < 2; ++nt)
      #pragma unroll
      for (int j = 0; j < 4; ++j)
        mreg[nt * 4 + j] =
          mg[(size_t)(16 * wq + 4 * lhi + j) * S_ + kt * BN + 16 * nt + llo];

    // ---- QK^T: 16 q-rows x 32 k-cols per wave ----
    f32x4 sacc[2];
    sacc[0] = (f32x4){0.f,0.f,0.f,0.f}; sacc[1] = sacc[0];
    #pragma unroll
    for (int ks = 0; ks < 4; ++ks) {
      s16x8 bfr[2];
      #pragma unroll
      for (int nt = 0; nt < 2; ++nt)
        bfr[nt] = *(s16x8*)(lKc + (ks * 2 + nt) * 1024 + lane * 16);
      #pragma unroll
      for (int nt = 0; nt < 2; ++nt)
        sacc[nt] = __builtin_amdgcn_mfma_f32_16x16x32_bf16(qf[ks], bfr[nt], sacc[nt], 0, 0, 0);
    }

    // ---- write staged K into other buffer; issue V loads ----
    f32x4 vst[4];
    const float* vgt = vg + (size_t)(kt + 1) * BN * D_;
    if (pf) {
      char* lKn = lK0 + (cur ^ 1) * 8192;
      #pragma unroll
      for (int rep = 0; rep < 4; ++rep) {
        f32x4 x = kst[rep];
        s16x4 h; h[0]=f2bf(x[0]); h[1]=f2bf(x[1]); h[2]=f2bf(x[2]); h[3]=f2bf(x[3]);
        *(s16x4*)(lKn + K_O(rep)) = h;
      }
      #pragma unroll
      for (int rep = 0; rep < 4; ++rep) {
        int bid = (tid >> 2) + 64 * rep;
        int kb = bid >> 5, db = bid & 31, l2 = lane & 3;
        vst[rep] = *(const f32x4*)(vgt + (size_t)(kb * 4 + l2) * D_ + db * 4);
      }
    }

    // ---- clip + mask from sacc -> lS only (bf16, fragment-major) ----
    #pragma unroll
    for (int nt = 0; nt < 2; ++nt) {
      char* sb = lS + (2 * nt + (llo >> 3)) * 256 + (llo & 7) * 2;
      #pragma unroll
      for (int j = 0; j < 4; ++j) {
        float val = fminf(fmaxf(sacc[nt][j], 0.f), 15.f);
        if (mreg[nt * 4 + j] == 0) val = 0.f;
        *(uint16_t*)(sb + (4 * lhi + j) * 16) = f2bf(val);
      }
    }

    // ---- PV: O[16 x 128] += S @ V^T (single K=32 step) ----
    {
      s16x8 saf = *(s16x8*)(lS + lane * 16);
      #pragma unroll
      for (int nt = 0; nt < 8; ++nt) {
        s16x8 vb = *(s16x8*)(lVc + nt * 1024 + lane * 16);
        oacc[nt] = __builtin_amdgcn_mfma_f32_16x16x32_bf16(saf, vb, oacc[nt], 0, 0, 0);
      }
    }

    // ---- attn repack: lS -> f32, 1KB contiguous per instruction ----
    // lane covers (r = 16wq + p*8 + lane/8, cols cb*4..cb*4+3), cb = lane&7.
    // Per instruction the wave writes 8 full 128B-aligned line-halves... no:
    // 8 rows x 32 cols covered per p across the wave = 8 x 128B full segments.
    #pragma unroll
    for (int p = 0; p < 2; ++p) {
      int r  = 16 * wq + p * 8 + (lane >> 3);
      int cb = lane & 7;
      s16x4 sv = *(s16x4*)(lS + (cb >> 1) * 256 + ((r & 15) * 16) + (cb & 1) * 8);
      f32x4 a;
      a[0]=bf2f((uint16_t)sv[0]); a[1]=bf2f((uint16_t)sv[1]);
      a[2]=bf2f((uint16_t)sv[2]); a[3]=bf2f((uint16_t)sv[3]);
      __builtin_nontemporal_store(a, (f32x4*)(ag + (size_t)r * S_ + kt * BN + cb * 4));
    }

    // ---- transpose + write staged V into other buffer ----
    if (pf) {
      char* lVn = lV0 + (cur ^ 1) * 8192;
      #pragma unroll
      for (int rep = 0; rep < 4; ++rep) {
        int bid = (tid >> 2) + 64 * rep;
        int kb = bid >> 5, db = bid & 31, l2 = lane & 3;
        f32x4 x = vst[rep];
        float v0=x[0], v1=x[1], v2=x[2], v3=x[3], t;
        t=(l2&1)?v0:v1; t=__shfl_xor(t,1); if(l2&1)v0=t; else v1=t;
        t=(l2&1)?v2:v3; t=__shfl_xor(t,1); if(l2&1)v2=t; else v3=t;
        t=(l2&2)?v0:v2; t=__shfl_xor(t,2); if(l2&2)v0=t; else v2=t;
        t=(l2&2)?v1:v3; t=__shfl_xor(t,2); if(l2&2)v1=t; else v3=t;
        int dd = db * 4 + l2;
        s16x4 h; h[0]=f2bf(v0); h[1]=f2bf(v1); h[2]=f2bf(v2); h[3]=f2bf(v3);
        *(s16x4*)(lVn + (dd >> 4) * 1024 + ((kb >> 1) & 3) * 256
                      + (dd & 15) * 16 + (kb & 1) * 8) = h;
      }
    }

    LDS_BARRIER();   // the ONE barrier per K-tile; vmcnt never drained
    cur ^= 1;
  }

  // ---- epilogue: O store ----
  #pragma unroll
  for (int nt = 0; nt < 8; ++nt) {
    int n = 16 * nt + llo;
    #pragma unroll
    for (int j = 0; j < 4; ++j) {
      int m = 16 * wq + 4 * lhi + j;
      __builtin_nontemporal_store(oacc[nt][j], og + (size_t)m * D_ + n);
    }
  }
}

extern "C" void kernel_launch(void* const* d_in, const int* in_sizes, int n_in,
                              void* d_out, int out_size, void* d_ws, size_t ws_size,
                              hipStream_t stream) {
  const float* q    = (const float*)d_in[0];
  const float* k    = (const float*)d_in[1];
  const float* v    = (const float*)d_in[2];
  const int*   mask = (const int*)d_in[3];
  float* outp  = (float*)d_out;
  float* attnp = outp + (size_t)B_ * H_ * S_ * D_;   // tuple: (out, attn) concat
  dim3 grid(B_ * H_ * (S_ / BM));                    // 1024 blocks
  attn_relu15_kernel<<<grid, NTHREADS, 0, stream>>>(q, k, v, mask, outp, attnp);
}

// Round 6
// 101.494 us; speedup vs baseline: 2.5855x; 1.2402x over previous
//
#include <hip/hip_runtime.h>
#include <stdint.h>

// Shapes (fixed for this problem)
#define B_   4
#define H_   16
#define S_   1024
#define D_   128
#define BM   64                  // Q rows per block
#define BN   32                  // K/V rows per iteration
#define NKT  (S_ / BN)           // 32
#define NTHREADS 256             // 4 waves; each wave owns 16 q-rows

typedef float f32x4 __attribute__((ext_vector_type(4)));
typedef short s16x8 __attribute__((ext_vector_type(8)));   // 8 bf16 (MFMA A/B frag)
typedef short s16x4 __attribute__((ext_vector_type(4)));

static __device__ __forceinline__ uint16_t f2bf(float f) {
  uint32_t u = __float_as_uint(f);
  u += 0x7FFFu + ((u >> 16) & 1u);          // round-to-nearest-even
  return (uint16_t)(u >> 16);
}
static __device__ __forceinline__ float bf2f(uint16_t h) {
  return __uint_as_float((uint32_t)h << 16);
}

// Direct global->LDS DMA, 16B per lane. LDS dst = wave-uniform base + lane*16
// (HW rule); global src is per-lane. Our ws tiles are pre-laid in LDS byte
// order, so src offset == dst offset (both linear).
static __device__ __forceinline__ void gl16(const void* g, void* l) {
  __builtin_amdgcn_global_load_lds(
      (const __attribute__((address_space(1))) unsigned int*)g,
      (__attribute__((address_space(3))) unsigned int*)l, 16, 0, 0);
}

// ws layout: [0,16M) Kbf tiles, [16M,32M) Vbf tiles, [32M,32.5M) mask bitwords.
// K tile (bh,kt): 8192B; chunk16B[(ks*2+nt)*64 + lane] = K[kt*32+16nt+llo][32ks+8lhi..+7]
// V tile (bh,kt): 8192B; chunk16B[nt*64 + lane]        = V[kt*32+8lhi..+7][16nt+llo]
// mask word [b*1024+r][w] = bits of mask[b][r][32w..32w+31]
#define WSK_BYTES  16777216
#define WSV_BYTES  16777216
#define WSM_BYTES  524288
#define WS_NEED    (WSK_BYTES + WSV_BYTES + WSM_BYTES)

// ============================ pre-pass ====================================
__global__ __launch_bounds__(256)
void prepass_kernel(const float* __restrict__ k, const float* __restrict__ v,
                    const int* __restrict__ mask,
                    char* __restrict__ wsK, char* __restrict__ wsV,
                    uint32_t* __restrict__ wsM)
{
  int gid = blockIdx.x * 256 + threadIdx.x;
  if (gid < 1048576) {                       // ---- K chunks ----
    int tile = gid >> 9, c = gid & 511;
    int ks = c >> 7, nt = (c >> 6) & 1, lane = c & 63;
    int row = (tile & 31) * 32 + 16 * nt + (lane & 15);
    int col = 32 * ks + 8 * (lane >> 4);
    const float* src = k + ((size_t)(tile >> 5) * S_ + row) * D_ + col;
    f32x4 x0 = *(const f32x4*)src;
    f32x4 x1 = *(const f32x4*)(src + 4);
    s16x8 h;
    h[0]=f2bf(x0[0]); h[1]=f2bf(x0[1]); h[2]=f2bf(x0[2]); h[3]=f2bf(x0[3]);
    h[4]=f2bf(x1[0]); h[5]=f2bf(x1[1]); h[6]=f2bf(x1[2]); h[7]=f2bf(x1[3]);
    *(s16x8*)(wsK + (size_t)gid * 16) = h;
  } else if (gid < 2097152) {                // ---- V chunks (transposed) ----
    int gv = gid - 1048576;
    int tile = gv >> 9, c = gv & 511;
    int nt = c >> 6, lane = c & 63;
    int d   = 16 * nt + (lane & 15);
    int kv0 = (tile & 31) * 32 + 8 * (lane >> 4);
    const float* src = v + ((size_t)(tile >> 5) * S_ + kv0) * D_ + d;
    s16x8 h;
    #pragma unroll
    for (int i = 0; i < 8; ++i) h[i] = f2bf(src[(size_t)i * D_]);
    *(s16x8*)(wsV + (size_t)gv * 16) = h;
  } else if (gid < 2228224) {                // ---- mask bitwords ----
    int gm = gid - 2097152;                  // = (b*1024 + r)*32 + w
    const int* src = mask + (size_t)(gm >> 5) * S_ + (gm & 31) * 32;
    uint32_t bits = 0;
    #pragma unroll
    for (int i = 0; i < 32; ++i) bits |= (src[i] != 0 ? 1u : 0u) << i;
    wsM[gm] = bits;
  }
}

// ============================ main kernel =================================
// LDS map (36864 B -> 4 blocks/CU, 16 waves/CU):
//  [    0,16384) lK dbuf (8KB each), fragment-major (see ws layout)
//  [16384,32768) lV dbuf (8KB each), fragment-major
//  [32768,36864) lS: per wave 1KB; chunk16B[lane] = S[q=llo][kv=8lhi..+7]
__global__ __launch_bounds__(NTHREADS)
__attribute__((amdgpu_waves_per_eu(4, 4)))
void attn_relu15_main(const float* __restrict__ q,
                      const char* __restrict__ wsK, const char* __restrict__ wsV,
                      const uint32_t* __restrict__ wsM,
                      float* __restrict__ outp, float* __restrict__ attnp)
{
  const int blk = blockIdx.x;
  const int g   = (blk & 7) * 128 + (blk >> 3);   // XCD-grouped bijection
  const int bh  = g >> 4;
  const int qt  = g & 15;
  const int b   = bh >> 4;

  const int tid  = threadIdx.x;
  const int lane = tid & 63;
  const int wq   = tid >> 6;
  const int lhi  = lane >> 4;
  const int llo  = lane & 15;

  __shared__ __align__(16) char smem[36864];
  char* const lK0 = smem;
  char* const lV0 = smem + 16384;
  char* const lS  = smem + 32768 + wq * 1024;

  const float*    qg = q + (size_t)bh * (S_ * D_) + (size_t)qt * BM * D_;
  const char*     kw = wsK + (size_t)(bh * 32) * 8192;
  const char*     vw = wsV + (size_t)(bh * 32) * 8192;
  const uint32_t* mw0 = wsM + ((size_t)b * S_ + qt * BM + 16 * wq) * 32;
  float*          ag = attnp + (size_t)bh * S_ * S_ + (size_t)qt * BM * S_;
  float*          og = outp  + (size_t)bh * (S_ * D_) + (size_t)qt * BM * D_;

  const float invT = 0.08838834764831843f;   // 1/sqrt(128)

  // ---- Q fragments into registers (scaled, bf16), loaded once ----
  s16x8 qf[4];
  {
    const float* qrow = qg + (size_t)(16 * wq + llo) * D_;
    #pragma unroll
    for (int ks = 0; ks < 4; ++ks) {
      int d0 = 32 * ks + 8 * lhi;
      f32x4 x0 = *(const f32x4*)(qrow + d0);
      f32x4 x1 = *(const f32x4*)(qrow + d0 + 4);
      s16x8 h;
      h[0]=f2bf(x0[0]*invT); h[1]=f2bf(x0[1]*invT); h[2]=f2bf(x0[2]*invT); h[3]=f2bf(x0[3]*invT);
      h[4]=f2bf(x1[0]*invT); h[5]=f2bf(x1[1]*invT); h[6]=f2bf(x1[2]*invT); h[7]=f2bf(x1[3]*invT);
      qf[ks] = h;
    }
  }

  // ---- prologue: DMA tile 0 into buffer 0 ----
  #pragma unroll
  for (int rep = 0; rep < 2; ++rep) {
    gl16(kw + rep * 4096 + tid * 16, lK0 + rep * 4096 + wq * 1024);
    gl16(vw + rep * 4096 + tid * 16, lV0 + rep * 4096 + wq * 1024);
  }
  asm volatile("s_waitcnt vmcnt(0) lgkmcnt(0)" ::: "memory");
  __builtin_amdgcn_s_barrier();
  __builtin_amdgcn_sched_barrier(0);

  f32x4 oacc[8];
  #pragma unroll
  for (int i = 0; i < 8; ++i) oacc[i] = (f32x4){0.f,0.f,0.f,0.f};

  int cur = 0;
  for (int kt = 0; kt < NKT; ++kt) {
    const bool pf = (kt + 1 < NKT);
    char* lKc = lK0 + cur * 8192;
    char* lVc = lV0 + cur * 8192;

    // ---- (1) mask bitword loads (oldest vmem ops this iter) ----
    uint32_t mwv[4];
    #pragma unroll
    for (int j = 0; j < 4; ++j)
      mwv[j] = mw0[(size_t)(4 * lhi + j) * 32 + kt];

    // ---- (2) DMA next tile into other buffer (stays in flight all iter) ----
    if (pf) {
      const char* kn = kw + (size_t)(kt + 1) * 8192;
      const char* vn = vw + (size_t)(kt + 1) * 8192;
      char* lKn = lK0 + (cur ^ 1) * 8192;
      char* lVn = lV0 + (cur ^ 1) * 8192;
      #pragma unroll
      for (int rep = 0; rep < 2; ++rep) {
        gl16(kn + rep * 4096 + tid * 16, lKn + rep * 4096 + wq * 1024);
        gl16(vn + rep * 4096 + tid * 16, lVn + rep * 4096 + wq * 1024);
      }
    }
    __builtin_amdgcn_sched_barrier(0);   // pin: nothing below moves above DMA

    // ---- (3) QK^T: 16 q-rows x 32 k-cols per wave ----
    f32x4 sacc[2];
    sacc[0] = (f32x4){0.f,0.f,0.f,0.f}; sacc[1] = sacc[0];
    #pragma unroll
    for (int ks = 0; ks < 4; ++ks) {
      s16x8 bfr[2];
      #pragma unroll
      for (int nt = 0; nt < 2; ++nt)
        bfr[nt] = *(s16x8*)(lKc + (ks * 2 + nt) * 1024 + lane * 16);
      #pragma unroll
      for (int nt = 0; nt < 2; ++nt)
        sacc[nt] = __builtin_amdgcn_mfma_f32_16x16x32_bf16(qf[ks], bfr[nt], sacc[nt], 0, 0, 0);
    }

    // ---- (4) clip + mask -> lS (bf16, fragment-major) ----
    #pragma unroll
    for (int nt = 0; nt < 2; ++nt) {
      char* sb = lS + (2 * nt + (llo >> 3)) * 256 + (llo & 7) * 2;
      #pragma unroll
      for (int j = 0; j < 4; ++j) {
        float val = fminf(fmaxf(sacc[nt][j], 0.f), 15.f);
        if (!((mwv[j] >> (16 * nt + llo)) & 1u)) val = 0.f;
        *(uint16_t*)(sb + (4 * lhi + j) * 16) = f2bf(val);
      }
    }

    // ---- (5) attn repack: lS -> f32, 128B row segments, issued early ----
    #pragma unroll
    for (int p = 0; p < 2; ++p) {
      int r  = 16 * wq + p * 8 + (lane >> 3);
      int cb = lane & 7;
      s16x4 sv = *(s16x4*)(lS + (cb >> 1) * 256 + ((r & 15) * 16) + (cb & 1) * 8);
      f32x4 a;
      a[0]=bf2f((uint16_t)sv[0]); a[1]=bf2f((uint16_t)sv[1]);
      a[2]=bf2f((uint16_t)sv[2]); a[3]=bf2f((uint16_t)sv[3]);
      __builtin_nontemporal_store(a, (f32x4*)(ag + (size_t)r * S_ + kt * BN + cb * 4));
    }

    // ---- (6) PV: O[16 x 128] += S @ V^T (single K=32 step) ----
    {
      s16x8 saf = *(s16x8*)(lS + lane * 16);
      #pragma unroll
      for (int nt = 0; nt < 8; ++nt) {
        s16x8 vb = *(s16x8*)(lVc + nt * 1024 + lane * 16);
        oacc[nt] = __builtin_amdgcn_mfma_f32_16x16x32_bf16(saf, vb, oacc[nt], 0, 0, 0);
      }
    }

    // ---- (7) barrier: wait DMA (4 ops) done, leave 2 attn stores in flight
    asm volatile("s_waitcnt vmcnt(2) lgkmcnt(0)" ::: "memory");
    __builtin_amdgcn_s_barrier();
    __builtin_amdgcn_sched_barrier(0);
    cur ^= 1;
  }

  // ---- epilogue: O store ----
  #pragma unroll
  for (int nt = 0; nt < 8; ++nt) {
    int n = 16 * nt + llo;
    #pragma unroll
    for (int j = 0; j < 4; ++j) {
      int m = 16 * wq + 4 * lhi + j;
      __builtin_nontemporal_store(oacc[nt][j], og + (size_t)m * D_ + n);
    }
  }
}

// ===================== fallback (r5 kernel, passing) ======================
#define LDS_BARRIER() do {                                   \
    asm volatile("s_waitcnt lgkmcnt(0)" ::: "memory");       \
    __builtin_amdgcn_s_barrier();                            \
    __builtin_amdgcn_sched_barrier(0);                       \
  } while (0)

__global__ __launch_bounds__(NTHREADS)
__attribute__((amdgpu_waves_per_eu(4, 4)))
void attn_relu15_fallback(const float* __restrict__ q, const float* __restrict__ k,
                          const float* __restrict__ v, const int* __restrict__ mask,
                          float* __restrict__ outp, float* __restrict__ attnp)
{
  const int blk = blockIdx.x;
  const int g   = (blk & 7) * 128 + (blk >> 3);
  const int bh  = g >> 4;
  const int qt  = g & 15;
  const int b   = bh >> 4;
  const int tid  = threadIdx.x;
  const int lane = tid & 63;
  const int wq   = tid >> 6;
  const int lhi  = lane >> 4;
  const int llo  = lane & 15;

  __shared__ __align__(16) char smem[36864];
  char* const lK0 = smem;
  char* const lV0 = smem + 16384;
  char* const lS  = smem + 32768 + wq * 1024;

  const float* qg = q + (size_t)bh * (S_ * D_) + (size_t)qt * BM * D_;
  const float* kg = k + (size_t)bh * (S_ * D_);
  const float* vg = v + (size_t)bh * (S_ * D_);
  const int*   mg = mask  + (size_t)b * S_ * S_ + (size_t)qt * BM * S_;
  float*       ag = attnp + (size_t)bh * S_ * S_ + (size_t)qt * BM * S_;
  float*       og = outp  + (size_t)bh * (S_ * D_) + (size_t)qt * BM * D_;
  const float invT = 0.08838834764831843f;

  #define K_O(rep)   ((tid + NTHREADS * (rep)) * 8)
  #define K_ROW(o)   ((((o) >> 10) & 1) * 16 + (((o) >> 4) & 15))
  #define K_COL(o)   (((o) >> 11) * 32 + (((o) >> 8) & 3) * 8 + (((o) >> 3) & 1) * 4)

  s16x8 qf[4];
  {
    const float* qrow = qg + (size_t)(16 * wq + llo) * D_;
    #pragma unroll
    for (int ks = 0; ks < 4; ++ks) {
      int d0 = 32 * ks + 8 * lhi;
      f32x4 x0 = *(const f32x4*)(qrow + d0);
      f32x4 x1 = *(const f32x4*)(qrow + d0 + 4);
      s16x8 h;
      h[0]=f2bf(x0[0]*invT); h[1]=f2bf(x0[1]*invT); h[2]=f2bf(x0[2]*invT); h[3]=f2bf(x0[3]*invT);
      h[4]=f2bf(x1[0]*invT); h[5]=f2bf(x1[1]*invT); h[6]=f2bf(x1[2]*invT); h[7]=f2bf(x1[3]*invT);
      qf[ks] = h;
    }
  }
  {
    #pragma unroll
    for (int rep = 0; rep < 4; ++rep) {
      int o = K_O(rep);
      f32x4 x = *(const f32x4*)(kg + K_ROW(o) * D_ + K_COL(o));
      s16x4 h; h[0]=f2bf(x[0]); h[1]=f2bf(x[1]); h[2]=f2bf(x[2]); h[3]=f2bf(x[3]);
      *(s16x4*)(lK0 + o) = h;
    }
    #pragma unroll
    for (int rep = 0; rep < 4; ++rep) {
      int bid = (tid >> 2) + 64 * rep;
      int kb = bid >> 5, db = bid & 31, l2 = lane & 3;
      f32x4 x = *(const f32x4*)(vg + (size_t)(kb * 4 + l2) * D_ + db * 4);
      float v0=x[0], v1=x[1], v2=x[2], v3=x[3], t;
      t=(l2&1)?v0:v1; t=__shfl_xor(t,1); if(l2&1)v0=t; else v1=t;
      t=(l2&1)?v2:v3; t=__shfl_xor(t,1); if(l2&1)v2=t; else v3=t;
      t=(l2&2)?v0:v2; t=__shfl_xor(t,2); if(l2&2)v0=t; else v2=t;
      t=(l2&2)?v1:v3; t=__shfl_xor(t,2); if(l2&2)v1=t; else v3=t;
      int dd = db * 4 + l2;
      s16x4 h; h[0]=f2bf(v0); h[1]=f2bf(v1); h[2]=f2bf(v2); h[3]=f2bf(v3);
      *(s16x4*)(lV0 + (dd >> 4) * 1024 + ((kb >> 1) & 3) * 256
                    + (dd & 15) * 16 + (kb & 1) * 8) = h;
    }
  }
  LDS_BARRIER();

  f32x4 oacc[8];
  #pragma unroll
  for (int i = 0; i < 8; ++i) oacc[i] = (f32x4){0.f,0.f,0.f,0.f};

  int cur = 0;
  for (int kt = 0; kt < NKT; ++kt) {
    const bool pf = (kt + 1 < NKT);
    char* lKc = lK0 + cur * 8192;
    char* lVc = lV0 + cur * 8192;
    f32x4 kst[4];
    const float* kgt = kg + (size_t)(kt + 1) * BN * D_;
    if (pf) {
      #pragma unroll
      for (int rep = 0; rep < 4; ++rep) {
        int o = K_O(rep);
        kst[rep] = *(const f32x4*)(kgt + K_ROW(o) * D_ + K_COL(o));
      }
    }
    int mreg[8];
    #pragma unroll
    for (int nt = 0; nt < 2; ++nt)
      #pragma unroll
      for (int j = 0; j < 4; ++j)
        mreg[nt * 4 + j] =
          mg[(size_t)(16 * wq + 4 * lhi + j) * S_ + kt * BN + 16 * nt + llo];

    f32x4 sacc[2];
    sacc[0] = (f32x4){0.f,0.f,0.f,0.f}; sacc[1] = sacc[0];
    #pragma unroll
    for (int ks = 0; ks < 4; ++ks) {
      s16x8 bfr[2];
      #pragma unroll
      for (int nt = 0; nt < 2; ++nt)
        bfr[nt] = *(s16x8*)(lKc + (ks * 2 + nt) * 1024 + lane * 16);
      #pragma unroll
      for (int nt = 0; nt < 2; ++nt)
        sacc[nt] = __builtin_amdgcn_mfma_f32_16x16x32_bf16(qf[ks], bfr[nt], sacc[nt], 0, 0, 0);
    }

    f32x4 vst[4];
    const float* vgt = vg + (size_t)(kt + 1) * BN * D_;
    if (pf) {
      char* lKn = lK0 + (cur ^ 1) * 8192;
      #pragma unroll
      for (int rep = 0; rep < 4; ++rep) {
        f32x4 x = kst[rep];
        s16x4 h; h[0]=f2bf(x[0]); h[1]=f2bf(x[1]); h[2]=f2bf(x[2]); h[3]=f2bf(x[3]);
        *(s16x4*)(lKn + K_O(rep)) = h;
      }
      #pragma unroll
      for (int rep = 0; rep < 4; ++rep) {
        int bid = (tid >> 2) + 64 * rep;
        int kb = bid >> 5, db = bid & 31, l2 = lane & 3;
        vst[rep] = *(const f32x4*)(vgt + (size_t)(kb * 4 + l2) * D_ + db * 4);
      }
    }

    #pragma unroll
    for (int nt = 0; nt < 2; ++nt) {
      char* sb = lS + (2 * nt + (llo >> 3)) * 256 + (llo & 7) * 2;
      #pragma unroll
      for (int j = 0; j < 4; ++j) {
        float val = fminf(fmaxf(sacc[nt][j], 0.f), 15.f);
        if (mreg[nt * 4 + j] == 0) val = 0.f;
        *(uint16_t*)(sb + (4 * lhi + j) * 16) = f2bf(val);
      }
    }
    {
      s16x8 saf = *(s16x8*)(lS + lane * 16);
      #pragma unroll
      for (int nt = 0; nt < 8; ++nt) {
        s16x8 vb = *(s16x8*)(lVc + nt * 1024 + lane * 16);
        oacc[nt] = __builtin_amdgcn_mfma_f32_16x16x32_bf16(saf, vb, oacc[nt], 0, 0, 0);
      }
    }
    #pragma unroll
    for (int p = 0; p < 2; ++p) {
      int r  = 16 * wq + p * 8 + (lane >> 3);
      int cb = lane & 7;
      s16x4 sv = *(s16x4*)(lS + (cb >> 1) * 256 + ((r & 15) * 16) + (cb & 1) * 8);
      f32x4 a;
      a[0]=bf2f((uint16_t)sv[0]); a[1]=bf2f((uint16_t)sv[1]);
      a[2]=bf2f((uint16_t)sv[2]); a[3]=bf2f((uint16_t)sv[3]);
      __builtin_nontemporal_store(a, (f32x4*)(ag + (size_t)r * S_ + kt * BN + cb * 4));
    }
    if (pf) {
      char* lVn = lV0 + (cur ^ 1) * 8192;
      #pragma unroll
      for (int rep = 0; rep < 4; ++rep) {
        int bid = (tid >> 2) + 64 * rep;
        int kb = bid >> 5, db = bid & 31, l2 = lane & 3;
        f32x4 x = vst[rep];
        float v0=x[0], v1=x[1], v2=x[2], v3=x[3], t;
        t=(l2&1)?v0:v1; t=__shfl_xor(t,1); if(l2&1)v0=t; else v1=t;
        t=(l2&1)?v2:v3; t=__shfl_xor(t,1); if(l2&1)v2=t; else v3=t;
        t=(l2&2)?v0:v2; t=__shfl_xor(t,2); if(l2&2)v0=t; else v2=t;
        t=(l2&2)?v1:v3; t=__shfl_xor(t,2); if(l2&2)v1=t; else v3=t;
        int dd = db * 4 + l2;
        s16x4 h; h[0]=f2bf(v0); h[1]=f2bf(v1); h[2]=f2bf(v2); h[3]=f2bf(v3);
        *(s16x4*)(lVn + (dd >> 4) * 1024 + ((kb >> 1) & 3) * 256
                      + (dd & 15) * 16 + (kb & 1) * 8) = h;
      }
    }
    LDS_BARRIER();
    cur ^= 1;
  }
  #pragma unroll
  for (int nt = 0; nt < 8; ++nt) {
    int n = 16 * nt + llo;
    #pragma unroll
    for (int j = 0; j < 4; ++j) {
      int m = 16 * wq + 4 * lhi + j;
      __builtin_nontemporal_store(oacc[nt][j], og + (size_t)m * D_ + n);
    }
  }
}

extern "C" void kernel_launch(void* const* d_in, const int* in_sizes, int n_in,
                              void* d_out, int out_size, void* d_ws, size_t ws_size,
                              hipStream_t stream) {
  const float* q    = (const float*)d_in[0];
  const float* k    = (const float*)d_in[1];
  const float* v    = (const float*)d_in[2];
  const int*   mask = (const int*)d_in[3];
  float* outp  = (float*)d_out;
  float* attnp = outp + (size_t)B_ * H_ * S_ * D_;   // tuple: (out, attn) concat

  if (ws_size >= (size_t)WS_NEED && d_ws != nullptr) {
    char*     wsK = (char*)d_ws;
    char*     wsV = wsK + WSK_BYTES;
    uint32_t* wsM = (uint32_t*)(wsK + WSK_BYTES + WSV_BYTES);
    prepass_kernel<<<8704, 256, 0, stream>>>(k, v, mask, wsK, wsV, wsM);
    attn_relu15_main<<<dim3(B_ * H_ * (S_ / BM)), NTHREADS, 0, stream>>>(
        q, wsK, wsV, wsM, outp, attnp);
  } else {
    attn_relu15_fallback<<<dim3(B_ * H_ * (S_ / BM)), NTHREADS, 0, stream>>>(
        q, k, v, mask, outp, attnp);
  }
}